// Round 4
// baseline (430.543 us; speedup 1.0000x reference)
//
#include <hip/hip_runtime.h>
#include <hip/hip_cooperative_groups.h>

namespace cg = cooperative_groups;

#define NBINS 256
#define NCOPY 32
#define GRID  1024
#define TPB   256

// Order-preserving float->uint encoding (monotone increasing).
__device__ __forceinline__ unsigned enc_f(float f) {
    unsigned u = __float_as_uint(f);
    return (u & 0x80000000u) ? ~u : (u | 0x80000000u);
}
__device__ __forceinline__ float dec_f(unsigned u) {
    unsigned v = (u & 0x80000000u) ? (u & 0x7FFFFFFFu) : ~u;
    return __uint_as_float(v);
}

// ws layout (uint32): [0..GRID-1] per-block min (enc), [GRID..2*GRID-1]
// per-block max (enc), [2*GRID..2*GRID+NBINS-1] hist bins.

__device__ __forceinline__ void minmax16(const float4& a, const float4& b,
                                         const float4& c, const float4& d,
                                         float& lmin, float& lmax) {
    float mn = fminf(fminf(fminf(a.x, a.y), fminf(a.z, a.w)),
                     fminf(fminf(b.x, b.y), fminf(b.z, b.w)));
    mn = fminf(mn, fminf(fminf(fminf(c.x, c.y), fminf(c.z, c.w)),
                         fminf(fminf(d.x, d.y), fminf(d.z, d.w))));
    float mx = fmaxf(fmaxf(fmaxf(a.x, a.y), fmaxf(a.z, a.w)),
                     fmaxf(fmaxf(b.x, b.y), fmaxf(b.z, b.w)));
    mx = fmaxf(mx, fmaxf(fmaxf(fmaxf(c.x, c.y), fmaxf(c.z, c.w)),
                         fmaxf(fmaxf(d.x, d.y), fmaxf(d.z, d.w))));
    lmin = fminf(lmin, mn);
    lmax = fmaxf(lmax, mx);
}

__global__ __launch_bounds__(TPB, 4) void hrt_fused(
        const float4* __restrict__ in4, long n4,
        const float* __restrict__ in, long n,
        unsigned* __restrict__ ws, float* __restrict__ out) {
    unsigned* pmin = ws;
    unsigned* pmax = ws + GRID;
    unsigned* hist = ws + 2 * GRID;

    __shared__ unsigned lh[NBINS * NCOPY];
    __shared__ unsigned sred[8];
    __shared__ unsigned sbc[2];

    cg::grid_group grid = cg::this_grid();
    const int tid = threadIdx.x;
    const int bid = blockIdx.x;
    const int wave = tid >> 6;
    const int lane = tid & 63;

    const long chunk = (n4 + GRID - 1) / GRID;
    const long lo = (long)bid * chunk;
    const long hi = (lo + chunk < n4) ? (lo + chunk) : n4;

    // ---------- phase 1: per-block min/max ----------
    float lmin = INFINITY, lmax = -INFINITY;
    {
        long i = lo + tid;
        for (; i + 3 * TPB < hi; i += 4 * TPB) {
            float4 a = in4[i], b = in4[i + TPB];
            float4 c = in4[i + 2 * TPB], d = in4[i + 3 * TPB];
            minmax16(a, b, c, d, lmin, lmax);
        }
        for (; i < hi; i += TPB) {
            float4 a = in4[i];
            lmin = fminf(lmin, fminf(fminf(a.x, a.y), fminf(a.z, a.w)));
            lmax = fmaxf(lmax, fmaxf(fmaxf(a.x, a.y), fmaxf(a.z, a.w)));
        }
    }
    if (bid == GRID - 1) {  // scalar tail (n % 4)
        for (long j = n4 * 4 + tid; j < n; j += TPB) {
            float v = in[j];
            lmin = fminf(lmin, v);
            lmax = fmaxf(lmax, v);
        }
    }
    unsigned emin = enc_f(lmin), emax = enc_f(lmax);
    #pragma unroll
    for (int off = 32; off > 0; off >>= 1) {
        emin = min(emin, (unsigned)__shfl_down((int)emin, off));
        emax = max(emax, (unsigned)__shfl_down((int)emax, off));
    }
    if (lane == 0) { sred[wave] = emin; sred[4 + wave] = emax; }
    __syncthreads();
    if (tid == 0) {
        unsigned m0 = min(min(sred[0], sred[1]), min(sred[2], sred[3]));
        unsigned m1 = max(max(sred[4], sred[5]), max(sred[6], sred[7]));
        atomicExch(&pmin[bid], m0);   // atomic write -> LLC-homed, no init needed
        atomicExch(&pmax[bid], m1);
    }
    // block 0 zeroes the global hist (atomic writes, LLC-homed)
    if (bid == 0) {
        for (int j = tid; j < NBINS; j += TPB) atomicExch(&hist[j], 0u);
    }
    __threadfence();
    grid.sync();   // release+acquire: partials visible to plain loads

    // ---------- phase 2: global min/max (plain cached loads) + histogram ----------
    for (int j = tid; j < NBINS * NCOPY; j += TPB) lh[j] = 0u;  // zero LDS hist

    // 1024 partial words per array = 256 threads x one uint4 each
    {
        uint4 a = ((const uint4*)pmin)[tid];
        uint4 b = ((const uint4*)pmax)[tid];
        unsigned gmin = min(min(a.x, a.y), min(a.z, a.w));
        unsigned gmax = max(max(b.x, b.y), max(b.z, b.w));
        #pragma unroll
        for (int off = 32; off > 0; off >>= 1) {
            gmin = min(gmin, (unsigned)__shfl_down((int)gmin, off));
            gmax = max(gmax, (unsigned)__shfl_down((int)gmax, off));
        }
        if (lane == 0) { sred[wave] = gmin; sred[4 + wave] = gmax; }
    }
    __syncthreads();  // lh zeroed + sred visible
    if (tid == 0) {
        sbc[0] = min(min(sred[0], sred[1]), min(sred[2], sred[3]));
        sbc[1] = max(max(sred[4], sred[5]), max(sred[6], sred[7]));
    }
    __syncthreads();
    const float tmin = dec_f(sbc[0]);
    const float tmax = dec_f(sbc[1]);
    const float scale = (float)NBINS / (tmax - tmin);
    const int copy = tid & (NCOPY - 1);

    #define HIST1(v)  do { \
        int ix = (int)(((v) - tmin) * scale); \
        ix = ix < 0 ? 0 : (ix > NBINS - 1 ? NBINS - 1 : ix); \
        atomicAdd(&lh[ix * NCOPY + copy], 1u); } while (0)
    #define HIST4(q)  do { HIST1((q).x); HIST1((q).y); HIST1((q).z); HIST1((q).w); } while (0)

    {
        long i = lo + tid;
        for (; i + 3 * TPB < hi; i += 4 * TPB) {
            float4 a = in4[i], b = in4[i + TPB];
            float4 c = in4[i + 2 * TPB], d = in4[i + 3 * TPB];
            HIST4(a); HIST4(b); HIST4(c); HIST4(d);
        }
        for (; i < hi; i += TPB) {
            float4 a = in4[i];
            HIST4(a);
        }
    }
    if (bid == GRID - 1) {  // scalar tail
        for (long j = n4 * 4 + tid; j < n; j += TPB) HIST1(in[j]);
    }
    __syncthreads();
    for (int b = tid; b < NBINS; b += TPB) {
        unsigned t = 0;
        #pragma unroll
        for (int c2 = 0; c2 < NCOPY; ++c2) {
            int cc = (c2 + lane) & (NCOPY - 1);
            t += lh[b * NCOPY + cc];
        }
        if (t) atomicAdd(&hist[b], t);
    }
    __threadfence();
    grid.sync();

    // ---------- phase 3: block 0 finalizes ----------
    if (bid == 0) {
        float* hf = (float*)lh;  // reuse LDS
        if (tid < NBINS) hf[tid] = (float)atomicAdd(&hist[tid], 0u);  // 256 atomic reads
        __syncthreads();
        if (tid == 0) {
            float total = 0.0f;
            for (int j = 0; j < NBINS; ++j) total += hf[j];
            float tl = total * (1.0f - 0.99f) / 2.0f;
            float tu = total * (1.0f + 0.99f) / 2.0f;
            int lower = -1, upper = -1;
            float cum = 0.0f;
            for (int j = 0; j < NBINS; ++j) {
                cum += hf[j];
                if (lower < 0 && cum > tl) lower = j;
                if (upper < 0 && cum > tu) upper = j;
            }
            if (lower < 0) lower = 0;
            if (upper < 0) upper = 0;
            float step = (tmax - tmin) / (float)NBINS;
            out[0] = tmin + step * (float)lower;
            out[1] = tmin + step * (float)upper;
        }
    }
    #undef HIST1
    #undef HIST4
}

// ---------------- fallback path (proven 4-kernel version) ----------------

__global__ void hrt_init(unsigned* __restrict__ ws) {
    int i = threadIdx.x;
    if (i == 0) { ws[0] = 0xFFFFFFFFu; ws[1] = 0u; }
    ws[2 + i] = 0u;
}

__global__ void hrt_minmax(const float4* __restrict__ in4, long n4,
                           const float* __restrict__ in, long n,
                           unsigned* __restrict__ ws) {
    float lmin = INFINITY, lmax = -INFINITY;
    long tid = (long)blockIdx.x * blockDim.x + threadIdx.x;
    long stride = (long)gridDim.x * blockDim.x;
    for (long i = tid; i < n4; i += stride) {
        float4 v = in4[i];
        lmin = fminf(lmin, fminf(fminf(v.x, v.y), fminf(v.z, v.w)));
        lmax = fmaxf(lmax, fmaxf(fmaxf(v.x, v.y), fmaxf(v.z, v.w)));
    }
    for (long i = n4 * 4 + tid; i < n; i += stride) {
        float v = in[i];
        lmin = fminf(lmin, v);
        lmax = fmaxf(lmax, v);
    }
    #pragma unroll
    for (int off = 32; off > 0; off >>= 1) {
        lmin = fminf(lmin, __shfl_down(lmin, off));
        lmax = fmaxf(lmax, __shfl_down(lmax, off));
    }
    __shared__ float smin[8], smax[8];
    int wave = threadIdx.x >> 6;
    int lane = threadIdx.x & 63;
    if (lane == 0) { smin[wave] = lmin; smax[wave] = lmax; }
    __syncthreads();
    if (threadIdx.x == 0) {
        int nw = blockDim.x >> 6;
        float bmin = smin[0], bmax = smax[0];
        for (int w = 1; w < nw; ++w) {
            bmin = fminf(bmin, smin[w]);
            bmax = fmaxf(bmax, smax[w]);
        }
        atomicMin(&ws[0], enc_f(bmin));
        atomicMax(&ws[1], enc_f(bmax));
    }
}

__global__ void hrt_hist(const float4* __restrict__ in4, long n4,
                         const float* __restrict__ in, long n,
                         unsigned* __restrict__ ws) {
    __shared__ unsigned lh[NBINS * NCOPY];
    for (int i = threadIdx.x; i < NBINS * NCOPY; i += blockDim.x) lh[i] = 0u;
    __syncthreads();
    float tmin = dec_f(ws[0]);
    float tmax = dec_f(ws[1]);
    float scale = (float)NBINS / (tmax - tmin);
    int copy = threadIdx.x & (NCOPY - 1);
    long tid = (long)blockIdx.x * blockDim.x + threadIdx.x;
    long stride = (long)gridDim.x * blockDim.x;
    for (long i = tid; i < n4; i += stride) {
        float4 v = in4[i];
        float c[4] = {v.x, v.y, v.z, v.w};
        #pragma unroll
        for (int k = 0; k < 4; ++k) {
            int idx = (int)((c[k] - tmin) * scale);
            idx = idx < 0 ? 0 : (idx > NBINS - 1 ? NBINS - 1 : idx);
            atomicAdd(&lh[idx * NCOPY + copy], 1u);
        }
    }
    for (long i = n4 * 4 + tid; i < n; i += stride) {
        int idx = (int)((in[i] - tmin) * scale);
        idx = idx < 0 ? 0 : (idx > NBINS - 1 ? NBINS - 1 : idx);
        atomicAdd(&lh[idx * NCOPY + copy], 1u);
    }
    __syncthreads();
    int lane = threadIdx.x & 63;
    for (int b = threadIdx.x; b < NBINS; b += blockDim.x) {
        unsigned t = 0;
        #pragma unroll
        for (int c = 0; c < NCOPY; ++c) {
            int cc = (c + lane) & (NCOPY - 1);
            t += lh[b * NCOPY + cc];
        }
        if (t) atomicAdd(&ws[2 + b], t);
    }
}

__global__ void hrt_finalize(const unsigned* __restrict__ ws,
                             float* __restrict__ out) {
    if (threadIdx.x != 0 || blockIdx.x != 0) return;
    float tmin = dec_f(ws[0]);
    float tmax = dec_f(ws[1]);
    float total = 0.0f;
    for (int i = 0; i < NBINS; ++i) total += (float)ws[2 + i];
    float tl = total * (1.0f - 0.99f) / 2.0f;
    float tu = total * (1.0f + 0.99f) / 2.0f;
    int lower = -1, upper = -1;
    float cum = 0.0f;
    for (int i = 0; i < NBINS; ++i) {
        cum += (float)ws[2 + i];
        if (lower < 0 && cum > tl) lower = i;
        if (upper < 0 && cum > tu) upper = i;
    }
    if (lower < 0) lower = 0;
    if (upper < 0) upper = 0;
    float step = (tmax - tmin) / (float)NBINS;
    out[0] = tmin + step * (float)lower;
    out[1] = tmin + step * (float)upper;
}

extern "C" void kernel_launch(void* const* d_in, const int* in_sizes, int n_in,
                              void* d_out, int out_size, void* d_ws, size_t ws_size,
                              hipStream_t stream) {
    const float* in = (const float*)d_in[0];
    long n = (long)in_sizes[0];
    long n4 = n / 4;
    unsigned* ws = (unsigned*)d_ws;
    float* out = (float*)d_out;

    const float4* in4 = (const float4*)in;
    void* args[] = {(void*)&in4, (void*)&n4, (void*)&in, (void*)&n,
                    (void*)&ws, (void*)&out};
    hipError_t e = hipLaunchCooperativeKernel((void*)hrt_fused, dim3(GRID), dim3(TPB),
                                              args, 0, stream);
    if (e != hipSuccess) {
        // fallback: proven 4-kernel path
        hrt_init<<<1, NBINS, 0, stream>>>(ws);
        const int threads = 256;
        const int blocks = 2048;
        hrt_minmax<<<blocks, threads, 0, stream>>>((const float4*)in, n4, in, n, ws);
        hrt_hist<<<blocks, threads, 0, stream>>>((const float4*)in, n4, in, n, ws);
        hrt_finalize<<<1, 1, 0, stream>>>(ws, out);
    }
}

// Round 5
// 291.438 us; speedup vs baseline: 1.4773x; 1.4773x over previous
//
#include <hip/hip_runtime.h>

#define NBINS 256
#define NCOPY 32
#define GRID1 2048
#define GRID2 2048
#define TPB   256

// Order-preserving float->uint encoding (monotone increasing).
__device__ __forceinline__ unsigned enc_f(float f) {
    unsigned u = __float_as_uint(f);
    return (u & 0x80000000u) ? ~u : (u | 0x80000000u);
}
__device__ __forceinline__ float dec_f(unsigned u) {
    unsigned v = (u & 0x80000000u) ? (u & 0x7FFFFFFFu) : ~u;
    return __uint_as_float(v);
}

// ws layout (uint32):
//   [0 .. GRID1)              per-block min (enc), plain-stored every call
//   [GRID1 .. 2*GRID1)        per-block max (enc)
//   [2*GRID1 .. 2*GRID1+256)  global hist bins (zeroed by pass1 block 0)
//   [2*GRID1+256]             completion counter (zeroed by pass1 block 0)

__device__ __forceinline__ void minmax16(const float4& a, const float4& b,
                                         const float4& c, const float4& d,
                                         float& lmin, float& lmax) {
    float mn = fminf(fminf(fminf(a.x, a.y), fminf(a.z, a.w)),
                     fminf(fminf(b.x, b.y), fminf(b.z, b.w)));
    mn = fminf(mn, fminf(fminf(fminf(c.x, c.y), fminf(c.z, c.w)),
                         fminf(fminf(d.x, d.y), fminf(d.z, d.w))));
    float mx = fmaxf(fmaxf(fmaxf(a.x, a.y), fmaxf(a.z, a.w)),
                     fmaxf(fmaxf(b.x, b.y), fmaxf(b.z, b.w)));
    mx = fmaxf(mx, fmaxf(fmaxf(fmaxf(c.x, c.y), fmaxf(c.z, c.w)),
                         fmaxf(fmaxf(d.x, d.y), fmaxf(d.z, d.w))));
    lmin = fminf(lmin, mn);
    lmax = fmaxf(lmax, mx);
}

__global__ __launch_bounds__(TPB) void hrt_pass1(
        const float4* __restrict__ in4, long n4,
        const float* __restrict__ in, long n,
        unsigned* __restrict__ pmin, unsigned* __restrict__ pmax,
        unsigned* __restrict__ hist, unsigned* __restrict__ cnt) {
    const int tid = threadIdx.x;
    const int bid = blockIdx.x;

    // block 0 re-inits the bins + counter for this call (LLC-homed atomics;
    // visible to pass2 across the kernel boundary)
    if (bid == 0) {
        for (int j = tid; j < NBINS; j += TPB) atomicExch(&hist[j], 0u);
        if (tid == 0) atomicExch(cnt, 0u);
    }

    float lmin = INFINITY, lmax = -INFINITY;
    const long stride = (long)GRID1 * TPB;
    long i = (long)bid * TPB + tid;
    for (; i + 3 * stride < n4; i += 4 * stride) {
        float4 a = in4[i];
        float4 b = in4[i + stride];
        float4 c = in4[i + 2 * stride];
        float4 d = in4[i + 3 * stride];
        minmax16(a, b, c, d, lmin, lmax);
    }
    for (; i < n4; i += stride) {
        float4 a = in4[i];
        lmin = fminf(lmin, fminf(fminf(a.x, a.y), fminf(a.z, a.w)));
        lmax = fmaxf(lmax, fmaxf(fmaxf(a.x, a.y), fmaxf(a.z, a.w)));
    }
    for (long j = n4 * 4 + (long)bid * TPB + tid; j < n; j += stride) {
        float v = in[j];
        lmin = fminf(lmin, v);
        lmax = fmaxf(lmax, v);
    }

    unsigned emin = enc_f(lmin), emax = enc_f(lmax);
    #pragma unroll
    for (int off = 32; off > 0; off >>= 1) {
        emin = min(emin, (unsigned)__shfl_down((int)emin, off));
        emax = max(emax, (unsigned)__shfl_down((int)emax, off));
    }
    __shared__ unsigned sred[8];
    const int wave = tid >> 6, lane = tid & 63;
    if (lane == 0) { sred[wave] = emin; sred[4 + wave] = emax; }
    __syncthreads();
    if (tid == 0) {
        unsigned m0 = min(min(sred[0], sred[1]), min(sred[2], sred[3]));
        unsigned m1 = max(max(sred[4], sred[5]), max(sred[6], sred[7]));
        pmin[bid] = m0;   // plain stores; kernel boundary publishes them
        pmax[bid] = m1;
    }
}

__global__ __launch_bounds__(TPB) void hrt_pass2(
        const float4* __restrict__ in4, long n4,
        const float* __restrict__ in, long n,
        const unsigned* __restrict__ pmin, const unsigned* __restrict__ pmax,
        unsigned* __restrict__ hist, unsigned* __restrict__ cnt,
        float* __restrict__ out) {
    __shared__ unsigned lh[NBINS * NCOPY];
    __shared__ unsigned sred[8];
    __shared__ unsigned sbc[2];
    __shared__ unsigned sIsLast;

    const int tid = threadIdx.x;
    const int bid = blockIdx.x;
    const int wave = tid >> 6, lane = tid & 63;

    for (int j = tid; j < NBINS * NCOPY; j += TPB) lh[j] = 0u;

    // reduce GRID1 partials per array: 512 uint4 words -> 256 threads x 2
    {
        const uint4* p4min = (const uint4*)pmin;
        const uint4* p4max = (const uint4*)pmax;
        uint4 a0 = p4min[tid], a1 = p4min[tid + TPB];
        uint4 b0 = p4max[tid], b1 = p4max[tid + TPB];
        unsigned gmin = min(min(min(a0.x, a0.y), min(a0.z, a0.w)),
                            min(min(a1.x, a1.y), min(a1.z, a1.w)));
        unsigned gmax = max(max(max(b0.x, b0.y), max(b0.z, b0.w)),
                            max(max(b1.x, b1.y), max(b1.z, b1.w)));
        #pragma unroll
        for (int off = 32; off > 0; off >>= 1) {
            gmin = min(gmin, (unsigned)__shfl_down((int)gmin, off));
            gmax = max(gmax, (unsigned)__shfl_down((int)gmax, off));
        }
        if (lane == 0) { sred[wave] = gmin; sred[4 + wave] = gmax; }
    }
    __syncthreads();
    if (tid == 0) {
        sbc[0] = min(min(sred[0], sred[1]), min(sred[2], sred[3]));
        sbc[1] = max(max(sred[4], sred[5]), max(sred[6], sred[7]));
    }
    __syncthreads();
    const float tmin = dec_f(sbc[0]);
    const float tmax = dec_f(sbc[1]);
    const float scale = (float)NBINS / (tmax - tmin);
    const int copy = tid & (NCOPY - 1);

    #define HIST1(v)  do { \
        int ix = (int)(((v) - tmin) * scale); \
        ix = ix < 0 ? 0 : (ix > NBINS - 1 ? NBINS - 1 : ix); \
        atomicAdd(&lh[ix * NCOPY + copy], 1u); } while (0)
    #define HIST4(q)  do { HIST1((q).x); HIST1((q).y); HIST1((q).z); HIST1((q).w); } while (0)

    {
        const long stride = (long)GRID2 * TPB;
        long i = (long)bid * TPB + tid;
        for (; i + 3 * stride < n4; i += 4 * stride) {
            float4 a = in4[i];
            float4 b = in4[i + stride];
            float4 c = in4[i + 2 * stride];
            float4 d = in4[i + 3 * stride];
            HIST4(a); HIST4(b); HIST4(c); HIST4(d);
        }
        for (; i < n4; i += stride) {
            float4 a = in4[i];
            HIST4(a);
        }
        for (long j = n4 * 4 + (long)bid * TPB + tid; j < n; j += stride)
            HIST1(in[j]);
    }
    __syncthreads();

    // merge LDS hist into global bins (one atomic per nonzero bin)
    for (int b = tid; b < NBINS; b += TPB) {
        unsigned t = 0;
        #pragma unroll
        for (int c2 = 0; c2 < NCOPY; ++c2) {
            int cc = (c2 + lane) & (NCOPY - 1);
            t += lh[b * NCOPY + cc];
        }
        if (t) atomicAdd(&hist[b], t);
    }

    // last block finalizes
    __threadfence();
    if (tid == 0) sIsLast = (atomicAdd(cnt, 1u) == GRID2 - 1) ? 1u : 0u;
    __syncthreads();
    if (sIsLast) {
        float* hf = (float*)lh;  // reuse LDS
        if (tid < NBINS) hf[tid] = (float)atomicAdd(&hist[tid], 0u);
        __syncthreads();
        if (tid == 0) {
            float total = 0.0f;
            for (int j = 0; j < NBINS; ++j) total += hf[j];
            float tl = total * (1.0f - 0.99f) / 2.0f;
            float tu = total * (1.0f + 0.99f) / 2.0f;
            int lower = -1, upper = -1;
            float cum = 0.0f;
            for (int j = 0; j < NBINS; ++j) {
                cum += hf[j];
                if (lower < 0 && cum > tl) lower = j;
                if (upper < 0 && cum > tu) upper = j;
            }
            if (lower < 0) lower = 0;
            if (upper < 0) upper = 0;
            float step = (tmax - tmin) / (float)NBINS;
            out[0] = tmin + step * (float)lower;
            out[1] = tmin + step * (float)upper;
        }
    }
    #undef HIST1
    #undef HIST4
}

extern "C" void kernel_launch(void* const* d_in, const int* in_sizes, int n_in,
                              void* d_out, int out_size, void* d_ws, size_t ws_size,
                              hipStream_t stream) {
    const float* in = (const float*)d_in[0];
    long n = (long)in_sizes[0];
    long n4 = n / 4;
    unsigned* ws = (unsigned*)d_ws;
    float* out = (float*)d_out;

    unsigned* pmin = ws;
    unsigned* pmax = ws + GRID1;
    unsigned* hist = ws + 2 * GRID1;
    unsigned* cnt  = ws + 2 * GRID1 + NBINS;

    hrt_pass1<<<GRID1, TPB, 0, stream>>>((const float4*)in, n4, in, n,
                                         pmin, pmax, hist, cnt);
    hrt_pass2<<<GRID2, TPB, 0, stream>>>((const float4*)in, n4, in, n,
                                         pmin, pmax, hist, cnt, out);
}